// Round 4
// baseline (131.326 us; speedup 1.0000x reference)
//
#include <hip/hip_runtime.h>

// Chamfer (bidirectional 1-NN mean of squared distances), two [16384,3] fp32 clouds.
// d(i,j) = |a_i|^2 + (|b_j|^2 - 2 a_i.b_j); row-min taken on t(j)=|b_j|^2-2a.b_j.
//
// Round-4: round-3's MPTS=8 spilled (VGPR_Count=36 < ~44 live floats; WRITE_SIZE
// doubled by +16MB = 131K threads x 128B scratch) and halved occupancy (512 blocks).
// Fixes:
//  - __launch_bounds__(256, 2): VGPR cap 128 -> all A-state stays in registers.
//  - CHUNK 512->256: grid back to 1024 blocks (4 blocks/CU, 16 waves/CU).
// Kept: float4 LDS element (one broadcast ds_read_b128/B-point), scalar v_fma_f32,
// B-pair + v_min3_f32 merge (3.5 VALU instr/pair), fused last-block reduce.

#define NPTS 16384
#define CHUNK 256
#define NCHUNKS (NPTS / CHUNK)          // 64
#define MPTS 8                          // A-points per thread
#define BLOCK 256
#define APT (BLOCK * MPTS)              // 2048 A-points per block
#define NATILES (NPTS / APT)            // 8
#define NBLOCKS (NATILES * NCHUNKS * 2) // 1024
#define CINIT 0x7F7F7F7Fu

__global__ __launch_bounds__(BLOCK, 2) void chamfer_fused(
    const float* __restrict__ P0, const float* __restrict__ P1,
    unsigned* __restrict__ dmin_all, unsigned* __restrict__ counter,
    float* __restrict__ out)
{
    const float* A;
    const float* B;
    unsigned* dmin;
    if (blockIdx.z == 0) { A = P0; B = P1; dmin = dmin_all; }
    else                 { A = P1; B = P0; dmin = dmin_all + NPTS; }

    __shared__ float4 sB[CHUNK];   // {-2bx, -2by, -2bz, |b|^2} per B-point

    const int tid = threadIdx.x;

    // Stage this B-chunk into LDS, pre-transformed (one point per thread).
    if (tid < CHUNK) {
        const int j0 = (blockIdx.y * CHUNK + tid) * 3;
        const float bx = B[j0 + 0];
        const float by = B[j0 + 1];
        const float bz = B[j0 + 2];
        sB[tid] = make_float4(-2.0f * bx, -2.0f * by, -2.0f * bz,
                              bx * bx + by * by + bz * bz);
    }
    __syncthreads();

    // 8 A-points per thread, kept fully in registers (launch_bounds caps at 128 VGPR).
    float ax[MPTS], ay[MPTS], az[MPTS], a2[MPTS], tmin[MPTS];
    const int ibase = blockIdx.x * APT + tid * MPTS;
#pragma unroll
    for (int m = 0; m < MPTS; ++m) {
        ax[m] = A[(ibase + m) * 3 + 0];
        ay[m] = A[(ibase + m) * 3 + 1];
        az[m] = A[(ibase + m) * 3 + 2];
        a2[m] = ax[m] * ax[m] + ay[m] * ay[m] + az[m] * az[m];
        tmin[m] = 3.0e38f;
    }

    // Inner loop: 2 broadcast ds_read_b128 per B-pair, then per A-point:
    // 6 v_fma_f32 + 1 v_min3_f32 = 3.5 VALU instr per pair.
#pragma unroll 2
    for (int q = 0; q < CHUNK / 2; ++q) {
        const float4 b0 = sB[2 * q];
        const float4 b1 = sB[2 * q + 1];
#pragma unroll
        for (int m = 0; m < MPTS; ++m) {
            float t0 = fmaf(az[m], b0.z, b0.w);
            t0 = fmaf(ay[m], b0.y, t0);
            t0 = fmaf(ax[m], b0.x, t0);
            float t1 = fmaf(az[m], b1.z, b1.w);
            t1 = fmaf(ay[m], b1.y, t1);
            t1 = fmaf(ax[m], b1.x, t1);
            tmin[m] = fminf(fminf(t0, t1), tmin[m]);   // -> v_min3_f32
        }
    }

    // Merge partial mins across chunks (d >= 0 after clamp -> uint order == float order).
#pragma unroll
    for (int m = 0; m < MPTS; ++m) {
        const float d = fmaxf(tmin[m] + a2[m], 0.0f);
        atomicMin(&dmin[ibase + m], __float_as_uint(d));
    }

    // ---- last-block-reduces ----
    __threadfence();
    __syncthreads();
    __shared__ unsigned s_old;
    if (tid == 0) s_old = atomicAdd(counter, 1u);
    __syncthreads();
    if (s_old != CINIT + (unsigned)NBLOCKS - 1u) return;

    __threadfence();
    double s = 0.0;
    for (int i = tid; i < 2 * NPTS; i += BLOCK) {
        const unsigned bits = __hip_atomic_load(&dmin_all[i], __ATOMIC_RELAXED,
                                                __HIP_MEMORY_SCOPE_AGENT);
        s += (double)__uint_as_float(bits);
    }
    __shared__ double sd[BLOCK];
    sd[tid] = s;
    __syncthreads();
    for (int off = BLOCK / 2; off > 0; off >>= 1) {
        if (tid < off) sd[tid] += sd[tid + off];
        __syncthreads();
    }
    // mean(dist0) + mean(dist1) = (sum0 + sum1) / NPTS  (N0 == N1)
    if (tid == 0) out[0] = (float)(sd[0] / (double)NPTS);
}

extern "C" void kernel_launch(void* const* d_in, const int* in_sizes, int n_in,
                              void* d_out, int out_size, void* d_ws, size_t ws_size,
                              hipStream_t stream)
{
    const float* P0 = (const float*)d_in[0];
    const float* P1 = (const float*)d_in[1];
    float* out = (float*)d_out;
    unsigned* dmin = (unsigned*)d_ws;            // 2*NPTS partial mins
    unsigned* counter = dmin + 2 * NPTS;         // arrival counter (starts at 0x7F7F7F7F)

    // One memset covers dmin init (0x7F7F7F7F = 3.39e38 > any dist) AND the counter
    // (counts up from 0x7F7F7F7F; last block sees CINIT + NBLOCKS - 1).
    hipMemsetAsync(dmin, 0x7F, (size_t)(2 * NPTS + 1) * sizeof(unsigned), stream);

    dim3 grid(NATILES, NCHUNKS, 2);   // 8 x 64 x 2 = 1024 blocks
    chamfer_fused<<<grid, BLOCK, 0, stream>>>(P0, P1, dmin, counter, out);
}